// Round 2
// baseline (1440.233 us; speedup 1.0000x reference)
//
#include <hip/hip_runtime.h>
#include <hip/hip_bf16.h>

#define T_TOK 4096   // B*L
#define L_SEQ 2048
#define NE 1024
#define DI 2048
#define DX 4096
#define DFF 4096

typedef __bf16 bf16x8 __attribute__((ext_vector_type(8)));
typedef float f32x4 __attribute__((ext_vector_type(4)));
typedef __hip_bfloat16 bf16;

// ---------------- elementwise converts ----------------
__global__ __launch_bounds__(256) void f2b_kernel(const float* __restrict__ src,
                                                  bf16* __restrict__ dst, int n) {
    int i = blockIdx.x * 256 + threadIdx.x;
    if (i < n) dst[i] = __float2bfloat16(src[i]);
}

// x_proj_w [96][2048] -> padded [128][2048] bf16 (zero rows 96..127)
__global__ __launch_bounds__(256) void padw_kernel(const float* __restrict__ src,
                                                   bf16* __restrict__ dst) {
    int i = blockIdx.x * 256 + threadIdx.x;  // 128*2048
    int r = i >> 11;
    int c = i & 2047;
    float v = (r < 96) ? src[r * 2048 + c] : 0.f;
    dst[i] = __float2bfloat16(v);
}

// ---------------- layernorm (1024 cols, f32 in, bf16 out) ----------------
__global__ __launch_bounds__(256) void ln_kernel(const float* __restrict__ src,
                                                 const float* __restrict__ w,
                                                 const float* __restrict__ b,
                                                 bf16* __restrict__ dst) {
    int row = blockIdx.x, tid = threadIdx.x;
    float4 v = ((const float4*)src)[row * 256 + tid];
    float s = v.x + v.y + v.z + v.w;
    float s2 = v.x * v.x + v.y * v.y + v.z * v.z + v.w * v.w;
#pragma unroll
    for (int o = 1; o < 64; o <<= 1) {
        s += __shfl_xor(s, o);
        s2 += __shfl_xor(s2, o);
    }
    __shared__ float red[8];
    int wv = tid >> 6;
    if ((tid & 63) == 0) { red[wv] = s; red[wv + 4] = s2; }
    __syncthreads();
    s = red[0] + red[1] + red[2] + red[3];
    s2 = red[4] + red[5] + red[6] + red[7];
    float mu = s * (1.f / 1024.f);
    float var = s2 * (1.f / 1024.f) - mu * mu;
    float rs = rsqrtf(var + 1e-5f);
    float4 wv4 = ((const float4*)w)[tid];
    float4 bv4 = ((const float4*)b)[tid];
    int base = row * 1024 + tid * 4;
    dst[base + 0] = __float2bfloat16((v.x - mu) * rs * wv4.x + bv4.x);
    dst[base + 1] = __float2bfloat16((v.y - mu) * rs * wv4.y + bv4.y);
    dst[base + 2] = __float2bfloat16((v.z - mu) * rs * wv4.z + bv4.z);
    dst[base + 3] = __float2bfloat16((v.w - mu) * rs * wv4.w + bv4.w);
}

// ---------------- bf16 MFMA GEMM: C[m,n] = sum_k A[m,k]*B[n,k] ----------------
// 128x128 tile, BK=64, 4 waves (2x2), each wave 64x64 = 4x4 frags of 16x16.
// LDS granule-XOR swizzle: 16B granule g of row r stored at g^(r&7).
__global__ __launch_bounds__(256) void gemm_bt(
    const bf16* __restrict__ A, int lda, const bf16* __restrict__ B, int ldb,
    int K, float* __restrict__ outF, bf16* __restrict__ outB, int ldc,
    const float* __restrict__ bias, const float* __restrict__ resid, int act) {
    __shared__ short sA[128 * 64];
    __shared__ short sB[128 * 64];
    int tid = threadIdx.x;
    int l = tid & 63;
    int w = tid >> 6;
    int wr = w >> 1, wc = w & 1;
    int rowA0 = blockIdx.y * 128;
    int rowB0 = blockIdx.x * 128;
    int sg = tid & 7;          // granule within row (8 bf16 = 16B)
    int srow = tid >> 3;       // 0..31, +q*32

    f32x4 acc[4][4] = {};

    for (int kt = 0; kt < K; kt += 64) {
        int4 ra[4], rb[4];
#pragma unroll
        for (int q = 0; q < 4; ++q) {
            int r = q * 32 + srow;
            ra[q] = *(const int4*)(A + (size_t)(rowA0 + r) * lda + kt + sg * 8);
            rb[q] = *(const int4*)(B + (size_t)(rowB0 + r) * ldb + kt + sg * 8);
        }
        __syncthreads();
#pragma unroll
        for (int q = 0; q < 4; ++q) {
            int r = q * 32 + srow;
            int quad = sg ^ (r & 7);
            *(int4*)(&sA[r * 64 + quad * 8]) = ra[q];
            *(int4*)(&sB[r * 64 + quad * 8]) = rb[q];
        }
        __syncthreads();
#pragma unroll
        for (int ks = 0; ks < 2; ++ks) {
            bf16x8 af[4], bg[4];
#pragma unroll
            for (int m = 0; m < 4; ++m) {
                int r = wr * 64 + m * 16 + (l & 15);
                int quad = (ks * 4 + (l >> 4)) ^ (r & 7);
                af[m] = __builtin_bit_cast(bf16x8, *(const int4*)(&sA[r * 64 + quad * 8]));
            }
#pragma unroll
            for (int n = 0; n < 4; ++n) {
                int r = wc * 64 + n * 16 + (l & 15);
                int quad = (ks * 4 + (l >> 4)) ^ (r & 7);
                bg[n] = __builtin_bit_cast(bf16x8, *(const int4*)(&sB[r * 64 + quad * 8]));
            }
#pragma unroll
            for (int m = 0; m < 4; ++m)
#pragma unroll
                for (int n = 0; n < 4; ++n)
                    acc[m][n] = __builtin_amdgcn_mfma_f32_16x16x32_bf16(
                        af[m], bg[n], acc[m][n], 0, 0, 0);
        }
    }
    // epilogue: D row=(lane>>4)*4+reg, col=lane&15 (m89-verified)
#pragma unroll
    for (int m = 0; m < 4; ++m) {
#pragma unroll
        for (int n = 0; n < 4; ++n) {
#pragma unroll
            for (int j = 0; j < 4; ++j) {
                int row = rowA0 + wr * 64 + m * 16 + (l >> 4) * 4 + j;
                int col = rowB0 + wc * 64 + n * 16 + (l & 15);
                float v = acc[m][n][j];
                if (bias) v += bias[col];
                if (act == 1) v = fmaxf(v, 0.f);
                else if (act == 2) v = (v > 20.f) ? v : log1pf(__expf(v));
                if (resid) v += resid[(size_t)row * ldc + col];
                if (outF) outF[(size_t)row * ldc + col] = v;
                if (outB) outB[(size_t)row * ldc + col] = __float2bfloat16(v);
            }
        }
    }
}

// ---------------- depthwise causal conv (k=4) + bias + SiLU ----------------
__global__ __launch_bounds__(256) void conv_silu_kernel(
    const float* __restrict__ xz, const float* __restrict__ cw,
    const float* __restrict__ cb, float* __restrict__ xif,
    bf16* __restrict__ xib) {
    int i = blockIdx.x * 256 + threadIdx.x;  // over T_TOK*DI
    int dd = i & 2047;
    int tt = i >> 11;
    int t = tt & 2047;  // within batch
    float4 w4 = ((const float4*)cw)[dd];
    float wj[4] = {w4.x, w4.y, w4.z, w4.w};
    float acc = cb[dd];
#pragma unroll
    for (int j = 0; j < 4; ++j) {
        int ts = t - 3 + j;
        if (ts >= 0) acc += wj[j] * xz[(size_t)(tt - 3 + j) * DX + dd];
    }
    float sv = acc / (1.f + __expf(-acc));
    xif[i] = sv;
    xib[i] = __float2bfloat16(sv);
}

// ---------------- selective scan ----------------
// block = 256 thr = 16 d x 16 s; grid = 2 batches * 128 d-blocks
__global__ __launch_bounds__(256) void scan_kernel(
    const float* __restrict__ dtf, const float* __restrict__ xif,
    const float* __restrict__ xdb, const float* __restrict__ A_log,
    float* __restrict__ ys) {
    int b = blockIdx.x >> 7;
    int d0 = (blockIdx.x & 127) * 16;
    int tid = threadIdx.x;
    int dl = tid >> 4, s = tid & 15;
    float Aval = -__expf(A_log[(d0 + dl) * 16 + s]);
    float h = 0.f;
    __shared__ float s_dt[64][16], s_x[64][16], s_B[64][16], s_C[64][16], s_y[64][16];
    const size_t tokBase = (size_t)b * L_SEQ;
    for (int t0 = 0; t0 < L_SEQ; t0 += 64) {
#pragma unroll
        for (int q = 0; q < 4; ++q) {
            int idx = q * 256 + tid;
            int tr = idx >> 4, c = idx & 15;
            size_t tok = tokBase + t0 + tr;
            s_dt[tr][c] = dtf[tok * DX + d0 + c];   // dt lives in xz xi-half, stride DX
            s_x[tr][c] = xif[tok * DI + d0 + c];
            s_B[tr][c] = xdb[tok * 128 + 64 + c];
            s_C[tr][c] = xdb[tok * 128 + 80 + c];
        }
        __syncthreads();
#pragma unroll 4
        for (int t = 0; t < 64; ++t) {
            float dtv = s_dt[t][dl];
            float xv = s_x[t][dl];
            float Bv = s_B[t][s];
            float Cv = s_C[t][s];
            float dA = __expf(dtv * Aval);
            h = fmaf(dA, h, dtv * xv * Bv);
            float p = h * Cv;
            p += __shfl_xor(p, 1);
            p += __shfl_xor(p, 2);
            p += __shfl_xor(p, 4);
            p += __shfl_xor(p, 8);
            if (s == 0) s_y[t][dl] = p;
        }
        __syncthreads();
#pragma unroll
        for (int q = 0; q < 4; ++q) {
            int idx = q * 256 + tid;
            int tr = idx >> 4, c = idx & 15;
            ys[(tokBase + t0 + tr) * DI + d0 + c] = s_y[tr][c];
        }
    }
}

// ---------------- gate: y = (ys + xi*Dskip) * silu(z) -> bf16 ----------------
__global__ __launch_bounds__(256) void gate_kernel(
    const float* __restrict__ ys, const float* __restrict__ xif,
    const float* __restrict__ xz, const float* __restrict__ Dskip,
    bf16* __restrict__ yb) {
    int i = blockIdx.x * 256 + threadIdx.x;  // over T_TOK*DI
    int dd = i & 2047;
    int tt = i >> 11;
    float yv = ys[i] + xif[i] * Dskip[dd];
    float zv = xz[(size_t)tt * DX + DI + dd];
    float g = zv / (1.f + __expf(-zv));
    yb[i] = __float2bfloat16(yv * g);
}

extern "C" void kernel_launch(void* const* d_in, const int* in_sizes, int n_in,
                              void* d_out, int out_size, void* d_ws, size_t ws_size,
                              hipStream_t stream) {
    (void)in_sizes; (void)n_in; (void)out_size; (void)ws_size;
    const float* x        = (const float*)d_in[0];
    const float* ln1_w    = (const float*)d_in[1];
    const float* ln1_b    = (const float*)d_in[2];
    const float* ln2_w    = (const float*)d_in[3];
    const float* ln2_b    = (const float*)d_in[4];
    const float* in_proj  = (const float*)d_in[5];
    const float* conv_w   = (const float*)d_in[6];
    const float* conv_b   = (const float*)d_in[7];
    const float* x_proj   = (const float*)d_in[8];
    const float* dt_proj  = (const float*)d_in[9];
    const float* dt_bias  = (const float*)d_in[10];
    const float* A_log    = (const float*)d_in[11];
    const float* Dskip    = (const float*)d_in[12];
    const float* out_proj = (const float*)d_in[13];
    const float* ffn_w1   = (const float*)d_in[14];
    const float* ffn_b1   = (const float*)d_in[15];
    const float* ffn_w2   = (const float*)d_in[16];
    const float* ffn_b2   = (const float*)d_in[17];
    float* out = (float*)d_out;

    char* ws = (char*)d_ws;
    size_t off = 0;
    auto alloc = [&](size_t bytes) -> void* {
        void* p = ws + off;
        off += (bytes + 255) & ~(size_t)255;
        return p;
    };
    bf16* ln1b = (bf16*)alloc((size_t)T_TOK * NE * 2);
    bf16* wip  = (bf16*)alloc((size_t)DX * NE * 2);
    bf16* wxp  = (bf16*)alloc((size_t)128 * DI * 2);
    bf16* wdt  = (bf16*)alloc((size_t)DI * 64 * 2);
    bf16* wop  = (bf16*)alloc((size_t)NE * DI * 2);
    bf16* wf1  = (bf16*)alloc((size_t)DFF * NE * 2);
    bf16* wf2  = (bf16*)alloc((size_t)NE * DFF * 2);
    float* xz  = (float*)alloc((size_t)T_TOK * DX * 4);
    float* xif = (float*)alloc((size_t)T_TOK * DI * 4);
    bf16* xib  = (bf16*)alloc((size_t)T_TOK * DI * 2);
    float* xdbf= (float*)alloc((size_t)T_TOK * 128 * 4);
    bf16* xdbb = (bf16*)alloc((size_t)T_TOK * 128 * 2);
    float* ysb = (float*)alloc((size_t)T_TOK * DI * 4);
    bf16* yb   = (bf16*)alloc((size_t)T_TOK * DI * 2);
    float* x2  = (float*)alloc((size_t)T_TOK * NE * 4);
    bf16* ln2b = (bf16*)alloc((size_t)T_TOK * NE * 2);
    bf16* h1b  = (bf16*)alloc((size_t)T_TOK * DFF * 2);
    // dt (f32, [T][DI]) is written into the xi-half of xz (dead after conv), stride DX
    float* dtf = xz;

    // weight converts
    f2b_kernel<<<(DX * NE + 255) / 256, 256, 0, stream>>>(in_proj, wip, DX * NE);
    padw_kernel<<<(128 * DI) / 256, 256, 0, stream>>>(x_proj, wxp);
    f2b_kernel<<<(DI * 64 + 255) / 256, 256, 0, stream>>>(dt_proj, wdt, DI * 64);
    f2b_kernel<<<(NE * DI + 255) / 256, 256, 0, stream>>>(out_proj, wop, NE * DI);
    f2b_kernel<<<(DFF * NE + 255) / 256, 256, 0, stream>>>(ffn_w1, wf1, DFF * NE);
    f2b_kernel<<<(NE * DFF + 255) / 256, 256, 0, stream>>>(ffn_w2, wf2, NE * DFF);

    // ln1
    ln_kernel<<<T_TOK, 256, 0, stream>>>(x, ln1_w, ln1_b, ln1b);
    // G1: xz = ln1 @ in_proj^T   [4096,4096] k=1024
    gemm_bt<<<dim3(DX / 128, T_TOK / 128), 256, 0, stream>>>(
        ln1b, NE, wip, NE, NE, xz, nullptr, DX, nullptr, nullptr, 0);
    // conv + silu -> xi (f32 + bf16)
    conv_silu_kernel<<<(T_TOK * DI) / 256, 256, 0, stream>>>(xz, conv_w, conv_b, xif, xib);
    // G2: xdb = xi @ x_proj^T  [4096,128(pad)] k=2048
    gemm_bt<<<dim3(1, T_TOK / 128), 256, 0, stream>>>(
        xib, DI, wxp, DI, DI, xdbf, xdbb, 128, nullptr, nullptr, 0);
    // G3: dt = softplus(dt_raw @ dt_proj^T + b)  [4096,2048] k=64 -> into xz xi-half
    gemm_bt<<<dim3(DI / 128, T_TOK / 128), 256, 0, stream>>>(
        xdbb, 128, wdt, 64, 64, dtf, nullptr, DX, dt_bias, nullptr, 2);
    // selective scan
    scan_kernel<<<256, 256, 0, stream>>>(dtf, xif, xdbf, A_log, ysb);
    // gate
    gate_kernel<<<(T_TOK * DI) / 256, 256, 0, stream>>>(ysb, xif, xz, Dskip, yb);
    // G4: x2 = y @ out_proj^T + x   [4096,1024] k=2048
    gemm_bt<<<dim3(NE / 128, T_TOK / 128), 256, 0, stream>>>(
        yb, DI, wop, DI, DI, x2, nullptr, NE, nullptr, x, 0);
    // ln2
    ln_kernel<<<T_TOK, 256, 0, stream>>>(x2, ln2_w, ln2_b, ln2b);
    // G5: h1 = relu(ln2 @ w1^T + b1) -> bf16  [4096,4096] k=1024
    gemm_bt<<<dim3(DFF / 128, T_TOK / 128), 256, 0, stream>>>(
        ln2b, NE, wf1, NE, NE, nullptr, h1b, DFF, ffn_b1, nullptr, 1);
    // G6: out = h1 @ w2^T + b2 + x2  [4096,1024] k=4096
    gemm_bt<<<dim3(NE / 128, T_TOK / 128), 256, 0, stream>>>(
        h1b, DFF, wf2, DFF, DFF, out, nullptr, NE, ffn_b2, x2, 0);
}

// Round 11
// 762.201 us; speedup vs baseline: 1.8896x; 1.8896x over previous
//
#include <hip/hip_runtime.h>
#include <hip/hip_bf16.h>

#define T_TOK 4096   // B*L
#define L_SEQ 2048
#define NE 1024
#define DI 2048
#define DX 4096
#define DFF 4096
#define NCH 32       // scan chunks per sequence
#define CLEN 64      // L_SEQ / NCH

typedef __bf16 bf16x8 __attribute__((ext_vector_type(8)));
typedef float f32x4 __attribute__((ext_vector_type(4)));
typedef __hip_bfloat16 bf16;

__device__ __forceinline__ void gload16(const void* g, void* l) {
    __builtin_amdgcn_global_load_lds(
        (const __attribute__((address_space(1))) unsigned int*)g,
        (__attribute__((address_space(3))) unsigned int*)l, 16, 0, 0);
}

// ---------------- elementwise converts ----------------
__global__ __launch_bounds__(256) void f2b_kernel(const float* __restrict__ src,
                                                  bf16* __restrict__ dst, int n) {
    int i = blockIdx.x * 256 + threadIdx.x;
    if (i < n) dst[i] = __float2bfloat16(src[i]);
}

__global__ __launch_bounds__(256) void zero_kernel(float* __restrict__ p, int n4) {
    int i = blockIdx.x * 256 + threadIdx.x;
    if (i < n4) ((float4*)p)[i] = make_float4(0.f, 0.f, 0.f, 0.f);
}

// x_proj_w [96][2048] -> padded [128][2048] bf16 (zero rows 96..127)
__global__ __launch_bounds__(256) void padw_kernel(const float* __restrict__ src,
                                                   bf16* __restrict__ dst) {
    int i = blockIdx.x * 256 + threadIdx.x;  // 128*2048
    int r = i >> 11;
    int c = i & 2047;
    float v = (r < 96) ? src[r * 2048 + c] : 0.f;
    dst[i] = __float2bfloat16(v);
}

// ---------------- layernorm (1024 cols, f32 in, bf16 out) ----------------
__global__ __launch_bounds__(256) void ln_kernel(const float* __restrict__ src,
                                                 const float* __restrict__ w,
                                                 const float* __restrict__ b,
                                                 bf16* __restrict__ dst) {
    int row = blockIdx.x, tid = threadIdx.x;
    float4 v = ((const float4*)src)[row * 256 + tid];
    float s = v.x + v.y + v.z + v.w;
    float s2 = v.x * v.x + v.y * v.y + v.z * v.z + v.w * v.w;
#pragma unroll
    for (int o = 1; o < 64; o <<= 1) {
        s += __shfl_xor(s, o);
        s2 += __shfl_xor(s2, o);
    }
    __shared__ float red[8];
    int wv = tid >> 6;
    if ((tid & 63) == 0) { red[wv] = s; red[wv + 4] = s2; }
    __syncthreads();
    s = red[0] + red[1] + red[2] + red[3];
    s2 = red[4] + red[5] + red[6] + red[7];
    float mu = s * (1.f / 1024.f);
    float var = s2 * (1.f / 1024.f) - mu * mu;
    float rs = rsqrtf(var + 1e-5f);
    float4 wv4 = ((const float4*)w)[tid];
    float4 bv4 = ((const float4*)b)[tid];
    int base = row * 1024 + tid * 4;
    dst[base + 0] = __float2bfloat16((v.x - mu) * rs * wv4.x + bv4.x);
    dst[base + 1] = __float2bfloat16((v.y - mu) * rs * wv4.y + bv4.y);
    dst[base + 2] = __float2bfloat16((v.z - mu) * rs * wv4.z + bv4.z);
    dst[base + 3] = __float2bfloat16((v.w - mu) * rs * wv4.w + bv4.w);
}

// ---------------- bf16 MFMA GEMM: C[m,n] = sum_k A[m,k]*B[n,k] ----------------
// m97 structure: 128x128 tile, BK=64, 4 waves (2x2), global_load_lds width=16,
// linear LDS [128][64]. act: 0 none, 1 relu, 2 softplus, 3 f32 atomicAdd (split-K).
__global__ __launch_bounds__(256) void gemm_bt(
    const bf16* __restrict__ A, int lda, const bf16* __restrict__ B, int ldb,
    int K, float* __restrict__ outF, bf16* __restrict__ outB, int ldc,
    const float* __restrict__ bias, const float* __restrict__ resid, int act) {
    __shared__ __align__(16) short sA[128 * 64];
    __shared__ __align__(16) short sB_[128 * 64];
    const int tid = threadIdx.x;
    const int l = tid & 63;
    const int w = tid >> 6;
    const int wr = w >> 1, wc = w & 1;
    const int rowA0 = blockIdx.y * 128;
    const int rowB0 = blockIdx.x * 128;
    const int lr = l >> 3;        // row within 8-row chunk
    const int lc = (l & 7) * 8;   // elem col offset (16B granule)
    const int klen = K / (int)gridDim.z;
    const int k0 = blockIdx.z * klen;

    f32x4 acc[4][4] = {};

    for (int kt = k0; kt < k0 + klen; kt += 64) {
#pragma unroll
        for (int q = 0; q < 4; ++q) {
            int i = w * 4 + q;  // 16-KB tile = 16 chunks of 64 lanes x 16B
            const bf16* ga = A + (size_t)(rowA0 + i * 8 + lr) * lda + kt + lc;
            const bf16* gb = B + (size_t)(rowB0 + i * 8 + lr) * ldb + kt + lc;
            gload16(ga, (char*)sA + i * 1024);
            gload16(gb, (char*)sB_ + i * 1024);
        }
        __syncthreads();  // drains vmcnt(0): LDS tiles complete
#pragma unroll
        for (int ks = 0; ks < 2; ++ks) {
            bf16x8 af[4], bg[4];
#pragma unroll
            for (int m = 0; m < 4; ++m) {
                int r = wr * 64 + m * 16 + (l & 15);
                int g = ks * 4 + (l >> 4);
                af[m] = __builtin_bit_cast(bf16x8, *(const int4*)(&sA[r * 64 + g * 8]));
            }
#pragma unroll
            for (int n = 0; n < 4; ++n) {
                int r = wc * 64 + n * 16 + (l & 15);
                int g = ks * 4 + (l >> 4);
                bg[n] = __builtin_bit_cast(bf16x8, *(const int4*)(&sB_[r * 64 + g * 8]));
            }
#pragma unroll
            for (int m = 0; m < 4; ++m)
#pragma unroll
                for (int n = 0; n < 4; ++n)
                    acc[m][n] = __builtin_amdgcn_mfma_f32_16x16x32_bf16(
                        af[m], bg[n], acc[m][n], 0, 0, 0);
        }
        __syncthreads();  // all waves done reading before next overwrite
    }
    // epilogue: D row=(lane>>4)*4+reg, col=lane&15 (m89-verified)
#pragma unroll
    for (int m = 0; m < 4; ++m) {
#pragma unroll
        for (int n = 0; n < 4; ++n) {
#pragma unroll
            for (int j = 0; j < 4; ++j) {
                int row = rowA0 + wr * 64 + m * 16 + (l >> 4) * 4 + j;
                int col = rowB0 + wc * 64 + n * 16 + (l & 15);
                float v = acc[m][n][j];
                size_t idx = (size_t)row * ldc + col;
                if (act == 3) {
                    atomicAdd(outF + idx, v);
                } else {
                    if (bias) v += bias[col];
                    if (act == 1) v = fmaxf(v, 0.f);
                    else if (act == 2) v = (v > 20.f) ? v : log1pf(__expf(v));
                    if (resid) v += resid[idx];
                    if (outF) outF[idx] = v;
                    if (outB) outB[idx] = __float2bfloat16(v);
                }
            }
        }
    }
}

// ---------------- depthwise causal conv (k=4) + bias + SiLU ----------------
__global__ __launch_bounds__(256) void conv_silu_kernel(
    const float* __restrict__ xz, const float* __restrict__ cw,
    const float* __restrict__ cb, float* __restrict__ xif,
    bf16* __restrict__ xib) {
    int i = blockIdx.x * 256 + threadIdx.x;  // over T_TOK*DI
    int dd = i & 2047;
    int tt = i >> 11;
    int t = tt & 2047;  // within batch
    float4 w4 = ((const float4*)cw)[dd];
    float wj[4] = {w4.x, w4.y, w4.z, w4.w};
    float acc = cb[dd];
#pragma unroll
    for (int j = 0; j < 4; ++j) {
        int ts = t - 3 + j;
        if (ts >= 0) acc += wj[j] * xz[(size_t)(tt - 3 + j) * DX + dd];
    }
    float sv = acc / (1.f + __expf(-acc));
    xif[i] = sv;
    xib[i] = __float2bfloat16(sv);
}

// ---------------- chunked selective scan ----------------
// Recurrence per (b,d,s): h <- exp(dt*A)*h + dt*x*B.  Chunk-affine: h_end = P*h0 + Q,
// P = exp(A * sum(dt)).  Pass1: per-chunk (P,Q) with h0=0.  Combine: scan chunks.
// Pass2: recompute with correct h0, emit y fused with gate.
// Layout: lane owns one d (16 s-chains in registers). Block=256 d, grid=(b,c,db).

#define SS1(s, Bv) { float e = __expf(dtv * Av[s]); hh[s] = fmaf(e, hh[s], tdx * (Bv)); }
#define SS2(s, Bv, Cv) { float e = __expf(dtv * Av[s]); hh[s] = fmaf(e, hh[s], tdx * (Bv)); \
                         if ((s) & 1) yp1 = fmaf(hh[s], (Cv), yp1); else yp0 = fmaf(hh[s], (Cv), yp0); }

__global__ __launch_bounds__(256) void scan1_kernel(
    const float* __restrict__ dtf, const float* __restrict__ xif,
    const float* __restrict__ xdbf, const float* __restrict__ A_log,
    float* __restrict__ PQ) {
    int b = blockIdx.x >> 8;
    int c = (blockIdx.x >> 3) & 31;
    int db = blockIdx.x & 7;
    int d = db * 256 + threadIdx.x;
    size_t tok0 = (size_t)b * L_SEQ + (size_t)c * CLEN;
    float Av[16];
    {
        const float4* ap = (const float4*)(A_log + (size_t)d * 16);
        float4 a0 = ap[0], a1 = ap[1], a2 = ap[2], a3 = ap[3];
        Av[0] = -__expf(a0.x); Av[1] = -__expf(a0.y); Av[2] = -__expf(a0.z); Av[3] = -__expf(a0.w);
        Av[4] = -__expf(a1.x); Av[5] = -__expf(a1.y); Av[6] = -__expf(a1.z); Av[7] = -__expf(a1.w);
        Av[8] = -__expf(a2.x); Av[9] = -__expf(a2.y); Av[10] = -__expf(a2.z); Av[11] = -__expf(a2.w);
        Av[12] = -__expf(a3.x); Av[13] = -__expf(a3.y); Av[14] = -__expf(a3.z); Av[15] = -__expf(a3.w);
    }
    float hh[16];
#pragma unroll
    for (int s = 0; s < 16; ++s) hh[s] = 0.f;
    float sdt = 0.f;
#pragma unroll 4
    for (int t = 0; t < CLEN; ++t) {
        float dtv = dtf[(tok0 + t) * DX + d];
        float xv  = xif[(tok0 + t) * DI + d];
        float tdx = dtv * xv;
        sdt += dtv;
        const float4* Bp = (const float4*)(xdbf + (tok0 + t) * 128 + 64);  // uniform
        float4 B0 = Bp[0], B1 = Bp[1], B2 = Bp[2], B3 = Bp[3];
        SS1(0, B0.x) SS1(1, B0.y) SS1(2, B0.z) SS1(3, B0.w)
        SS1(4, B1.x) SS1(5, B1.y) SS1(6, B1.z) SS1(7, B1.w)
        SS1(8, B2.x) SS1(9, B2.y) SS1(10, B2.z) SS1(11, B2.w)
        SS1(12, B3.x) SS1(13, B3.y) SS1(14, B3.z) SS1(15, B3.w)
    }
    size_t bd = (size_t)b * DI + d;
    float4* ob = (float4*)(PQ + (bd * NCH + c) * 32);
    ob[0] = make_float4(__expf(Av[0] * sdt), __expf(Av[1] * sdt), __expf(Av[2] * sdt), __expf(Av[3] * sdt));
    ob[1] = make_float4(__expf(Av[4] * sdt), __expf(Av[5] * sdt), __expf(Av[6] * sdt), __expf(Av[7] * sdt));
    ob[2] = make_float4(__expf(Av[8] * sdt), __expf(Av[9] * sdt), __expf(Av[10] * sdt), __expf(Av[11] * sdt));
    ob[3] = make_float4(__expf(Av[12] * sdt), __expf(Av[13] * sdt), __expf(Av[14] * sdt), __expf(Av[15] * sdt));
    ob[4] = make_float4(hh[0], hh[1], hh[2], hh[3]);
    ob[5] = make_float4(hh[4], hh[5], hh[6], hh[7]);
    ob[6] = make_float4(hh[8], hh[9], hh[10], hh[11]);
    ob[7] = make_float4(hh[12], hh[13], hh[14], hh[15]);
}

__global__ __launch_bounds__(256) void scanc_kernel(const float* __restrict__ PQ,
                                                    float* __restrict__ h0) {
    int g = blockIdx.x * 256 + threadIdx.x;  // (b*DI+d)*16 + s
    size_t bd = g >> 4;
    int s = g & 15;
    const float* p = PQ + bd * NCH * 32 + s;
    float* o = h0 + bd * NCH * 16 + s;
    float hs = 0.f;
#pragma unroll 4
    for (int c = 0; c < NCH; ++c) {
        o[c * 16] = hs;
        hs = fmaf(p[c * 32], hs, p[c * 32 + 16]);
    }
}

__global__ __launch_bounds__(256) void scan2_kernel(
    const float* __restrict__ dtf, const float* __restrict__ xif,
    const float* __restrict__ xdbf, const float* __restrict__ A_log,
    const float* __restrict__ h0, const float* __restrict__ xz,
    const float* __restrict__ Dskip, bf16* __restrict__ yb) {
    int b = blockIdx.x >> 8;
    int c = (blockIdx.x >> 3) & 31;
    int db = blockIdx.x & 7;
    int d = db * 256 + threadIdx.x;
    size_t tok0 = (size_t)b * L_SEQ + (size_t)c * CLEN;
    float Av[16];
    {
        const float4* ap = (const float4*)(A_log + (size_t)d * 16);
        float4 a0 = ap[0], a1 = ap[1], a2 = ap[2], a3 = ap[3];
        Av[0] = -__expf(a0.x); Av[1] = -__expf(a0.y); Av[2] = -__expf(a0.z); Av[3] = -__expf(a0.w);
        Av[4] = -__expf(a1.x); Av[5] = -__expf(a1.y); Av[6] = -__expf(a1.z); Av[7] = -__expf(a1.w);
        Av[8] = -__expf(a2.x); Av[9] = -__expf(a2.y); Av[10] = -__expf(a2.z); Av[11] = -__expf(a2.w);
        Av[12] = -__expf(a3.x); Av[13] = -__expf(a3.y); Av[14] = -__expf(a3.z); Av[15] = -__expf(a3.w);
    }
    size_t bd = (size_t)b * DI + d;
    float hh[16];
    {
        const float4* hb = (const float4*)(h0 + (bd * NCH + c) * 16);
        float4 h0v = hb[0], h1v = hb[1], h2v = hb[2], h3v = hb[3];
        hh[0] = h0v.x; hh[1] = h0v.y; hh[2] = h0v.z; hh[3] = h0v.w;
        hh[4] = h1v.x; hh[5] = h1v.y; hh[6] = h1v.z; hh[7] = h1v.w;
        hh[8] = h2v.x; hh[9] = h2v.y; hh[10] = h2v.z; hh[11] = h2v.w;
        hh[12] = h3v.x; hh[13] = h3v.y; hh[14] = h3v.z; hh[15] = h3v.w;
    }
    float Dsk = Dskip[d];
#pragma unroll 4
    for (int t = 0; t < CLEN; ++t) {
        float dtv = dtf[(tok0 + t) * DX + d];
        float xv  = xif[(tok0 + t) * DI + d];
        float zv  = xz[(tok0 + t) * DX + DI + d];
        float tdx = dtv * xv;
        const float4* Bp = (const float4*)(xdbf + (tok0 + t) * 128 + 64);  // uniform
        float4 B0 = Bp[0], B1 = Bp[1], B2 = Bp[2], B3 = Bp[3];
        float4 C0 = Bp[4], C1 = Bp[5], C2 = Bp[6], C3 = Bp[7];
        float yp0 = 0.f, yp1 = 0.f;
        SS2(0, B0.x, C0.x) SS2(1, B0.y, C0.y) SS2(2, B0.z, C0.z) SS2(3, B0.w, C0.w)
        SS2(4, B1.x, C1.x) SS2(5, B1.y, C1.y) SS2(6, B1.z, C1.z) SS2(7, B1.w, C1.w)
        SS2(8, B2.x, C2.x) SS2(9, B2.y, C2.y) SS2(10, B2.z, C2.z) SS2(11, B2.w, C2.w)
        SS2(12, B3.x, C3.x) SS2(13, B3.y, C3.y) SS2(14, B3.z, C3.z) SS2(15, B3.w, C3.w)
        float yv = yp0 + yp1 + xv * Dsk;
        float g = zv / (1.f + __expf(-zv));
        yb[(tok0 + t) * DI + d] = __float2bfloat16(yv * g);
    }
}

extern "C" void kernel_launch(void* const* d_in, const int* in_sizes, int n_in,
                              void* d_out, int out_size, void* d_ws, size_t ws_size,
                              hipStream_t stream) {
    (void)in_sizes; (void)n_in; (void)out_size; (void)ws_size;
    const float* x        = (const float*)d_in[0];
    const float* ln1_w    = (const float*)d_in[1];
    const float* ln1_b    = (const float*)d_in[2];
    const float* ln2_w    = (const float*)d_in[3];
    const float* ln2_b    = (const float*)d_in[4];
    const float* in_proj  = (const float*)d_in[5];
    const float* conv_w   = (const float*)d_in[6];
    const float* conv_b   = (const float*)d_in[7];
    const float* x_proj   = (const float*)d_in[8];
    const float* dt_proj  = (const float*)d_in[9];
    const float* dt_bias  = (const float*)d_in[10];
    const float* A_log    = (const float*)d_in[11];
    const float* Dskip    = (const float*)d_in[12];
    const float* out_proj = (const float*)d_in[13];
    const float* ffn_w1   = (const float*)d_in[14];
    const float* ffn_b1   = (const float*)d_in[15];
    const float* ffn_w2   = (const float*)d_in[16];
    const float* ffn_b2   = (const float*)d_in[17];
    float* out = (float*)d_out;

    char* ws = (char*)d_ws;
    size_t off = 0;
    auto alloc = [&](size_t bytes) -> void* {
        void* p = ws + off;
        off += (bytes + 255) & ~(size_t)255;
        return p;
    };
    bf16* ln1b = (bf16*)alloc((size_t)T_TOK * NE * 2);
    bf16* wip  = (bf16*)alloc((size_t)DX * NE * 2);
    bf16* wxp  = (bf16*)alloc((size_t)128 * DI * 2);
    bf16* wdt  = (bf16*)alloc((size_t)DI * 64 * 2);
    bf16* wop  = (bf16*)alloc((size_t)NE * DI * 2);
    bf16* wf1  = (bf16*)alloc((size_t)DFF * NE * 2);
    bf16* wf2  = (bf16*)alloc((size_t)NE * DFF * 2);
    float* xz  = (float*)alloc((size_t)T_TOK * DX * 4);
    float* xif = (float*)alloc((size_t)T_TOK * DI * 4);
    bf16* xib  = (bf16*)alloc((size_t)T_TOK * DI * 2);
    float* xdbf= (float*)alloc((size_t)T_TOK * 128 * 4);
    bf16* xdbb = (bf16*)alloc((size_t)T_TOK * 128 * 2);
    float* PQ  = (float*)alloc((size_t)2 * DI * NCH * 32 * 4);  // 16 MB
    float* h0  = (float*)alloc((size_t)2 * DI * NCH * 16 * 4);  // 8 MB
    bf16* yb   = (bf16*)alloc((size_t)T_TOK * DI * 2);
    float* x2  = (float*)alloc((size_t)T_TOK * NE * 4);
    bf16* ln2b = (bf16*)alloc((size_t)T_TOK * NE * 2);
    bf16* h1b  = (bf16*)alloc((size_t)T_TOK * DFF * 2);
    // dt (f32, [T][DI]) is written into the xi-half of xz (dead after conv), stride DX
    float* dtf = xz;

    // weight converts
    f2b_kernel<<<(DX * NE + 255) / 256, 256, 0, stream>>>(in_proj, wip, DX * NE);
    padw_kernel<<<(128 * DI) / 256, 256, 0, stream>>>(x_proj, wxp);
    f2b_kernel<<<(DI * 64 + 255) / 256, 256, 0, stream>>>(dt_proj, wdt, DI * 64);
    f2b_kernel<<<(NE * DI + 255) / 256, 256, 0, stream>>>(out_proj, wop, NE * DI);
    f2b_kernel<<<(DFF * NE + 255) / 256, 256, 0, stream>>>(ffn_w1, wf1, DFF * NE);
    f2b_kernel<<<(NE * DFF + 255) / 256, 256, 0, stream>>>(ffn_w2, wf2, NE * DFF);

    // ln1
    ln_kernel<<<T_TOK, 256, 0, stream>>>(x, ln1_w, ln1_b, ln1b);
    // G1: xz = ln1 @ in_proj^T   [4096,4096] k=1024
    gemm_bt<<<dim3(DX / 128, T_TOK / 128), 256, 0, stream>>>(
        ln1b, NE, wip, NE, NE, xz, nullptr, DX, nullptr, nullptr, 0);
    // conv + silu -> xi (f32 + bf16)
    conv_silu_kernel<<<(T_TOK * DI) / 256, 256, 0, stream>>>(xz, conv_w, conv_b, xif, xib);
    // G2: xdb = xi @ x_proj^T  [4096,128(pad)] k=2048, split-K=8 via atomicAdd
    zero_kernel<<<(T_TOK * 128 / 4 + 255) / 256, 256, 0, stream>>>(xdbf, T_TOK * 128 / 4);
    gemm_bt<<<dim3(1, T_TOK / 128, 8), 256, 0, stream>>>(
        xib, DI, wxp, DI, DI, xdbf, nullptr, 128, nullptr, nullptr, 3);
    f2b_kernel<<<(T_TOK * 128 + 255) / 256, 256, 0, stream>>>(xdbf, xdbb, T_TOK * 128);
    // G3: dt = softplus(dt_raw @ dt_proj^T + b)  [4096,2048] k=64 -> into xz xi-half
    gemm_bt<<<dim3(DI / 128, T_TOK / 128), 256, 0, stream>>>(
        xdbb, 128, wdt, 64, 64, dtf, nullptr, DX, dt_bias, nullptr, 2);
    // chunked scan: pass1 -> combine -> pass2 (gate fused)
    scan1_kernel<<<2 * NCH * 8, 256, 0, stream>>>(dtf, xif, xdbf, A_log, PQ);
    scanc_kernel<<<(2 * DI * 16) / 256, 256, 0, stream>>>(PQ, h0);
    scan2_kernel<<<2 * NCH * 8, 256, 0, stream>>>(dtf, xif, xdbf, A_log, h0, xz, Dskip, yb);
    // G4: x2 = y @ out_proj^T + x   [4096,1024] k=2048
    gemm_bt<<<dim3(NE / 128, T_TOK / 128), 256, 0, stream>>>(
        yb, DI, wop, DI, DI, x2, nullptr, NE, nullptr, x, 0);
    // ln2
    ln_kernel<<<T_TOK, 256, 0, stream>>>(x2, ln2_w, ln2_b, ln2b);
    // G5: h1 = relu(ln2 @ w1^T + b1) -> bf16  [4096,4096] k=1024
    gemm_bt<<<dim3(DFF / 128, T_TOK / 128), 256, 0, stream>>>(
        ln2b, NE, wf1, NE, NE, nullptr, h1b, DFF, ffn_b1, nullptr, 1);
    // G6: out = h1 @ w2^T + b2 + x2  [4096,1024] k=4096
    gemm_bt<<<dim3(NE / 128, T_TOK / 128), 256, 0, stream>>>(
        h1b, DFF, wf2, DFF, DFF, out, nullptr, NE, ffn_b2, x2, 0);
}